// Round 8
// baseline (507.271 us; speedup 1.0000x reference)
//
#include <hip/hip_runtime.h>
#include <hip/hip_fp16.h>
#include <math.h>

#define D_MODEL 1024
#define NH 16
#define HD 64
#define SEQ 2048
#define BATCH 2
#define MROWS (BATCH*SEQ)   // 4096
#define KDIM 1024

typedef unsigned short u16;
typedef __attribute__((ext_vector_type(8))) _Float16 h8;   // 8 f16 (4 VGPRs)
typedef __attribute__((ext_vector_type(8))) short s8v;
typedef __attribute__((ext_vector_type(4))) float f4v;

#define MFMAH(a, b, c) __builtin_amdgcn_mfma_f32_16x16x32_f16(a, b, c, 0, 0, 0)

__device__ __forceinline__ u16 f32_to_f16(float f) {
    return __half_as_ushort(__float2half(f));   // v_cvt_f16_f32, RNE
}

// convert 8 fp32 (two float4) -> 8 packed fp16 in an s8v
__device__ __forceinline__ s8v cvt8(float4 a, float4 b) {
    s8v r;
    r[0] = (short)f32_to_f16(a.x); r[1] = (short)f32_to_f16(a.y);
    r[2] = (short)f32_to_f16(a.z); r[3] = (short)f32_to_f16(a.w);
    r[4] = (short)f32_to_f16(b.x); r[5] = (short)f32_to_f16(b.y);
    r[6] = (short)f32_to_f16(b.z); r[7] = (short)f32_to_f16(b.w);
    return r;
}

// ---------------------------------------------------------------------------
// Fused QKV fp16 MFMA GEMM with INLINE fp32->fp16 staging conversion.
// Grid (32, 24): y>>3 selects Q/K/V, y&7 the 128-col n-tile.
// Q,K: fused RoPE -> fp16 [B,H,S,D]; K also atomicMax of row-norm^2 (RoPE-
// invariant) into km2. V: LDS transpose -> fp16 [B,H,D,S].
// ---------------------------------------------------------------------------
__global__ __launch_bounds__(256, 2)
void qkv_gemm(const float* __restrict__ x,
              const float* __restrict__ Wq, const float* __restrict__ Wk,
              const float* __restrict__ Wv,
              const float* __restrict__ bq, const float* __restrict__ bk,
              const float* __restrict__ bv,
              u16* __restrict__ QF, u16* __restrict__ KF,
              u16* __restrict__ VtF, float* __restrict__ km2) {
    __shared__ __align__(16) u16 SMEM[16384];   // 32 KB; K-loop uses first 16 KB
    u16* As = SMEM;                 // [128][32] f16
    u16* Bs = SMEM + 4096;

    const int t    = threadIdx.x;
    const int w    = t >> 6;
    const int lane = t & 63;
    const int quad = lane >> 4;
    const int l15  = lane & 15;
    const int wr   = w >> 1;
    const int wc   = w & 1;
    const int m0b  = blockIdx.x * 128;
    const int wsel = blockIdx.y >> 3;
    const int n0   = (blockIdx.y & 7) * 128;

    const float* Bg;
    const float* bias;
    if (wsel == 0)      { Bg = Wq; bias = bq; }
    else if (wsel == 1) { Bg = Wk; bias = bk; }
    else                { Bg = Wv; bias = bv; }

    const int srow = t >> 2;            // 0..63
    const int scol = (t & 3) * 8;       // 8 elems per thread
    const float* ag = x  + (size_t)(m0b + srow) * KDIM + scol;
    const float* bg = Bg + (size_t)(n0 + srow) * KDIM + scol;
    const size_t rstep = (size_t)64 * KDIM;

    f4v acc[4][4];
    #pragma unroll
    for (int i = 0; i < 4; i++)
        #pragma unroll
        for (int j = 0; j < 4; j++)
            acc[i][j] = (f4v){0.f, 0.f, 0.f, 0.f};

    for (int k0 = 0; k0 < KDIM; k0 += 32) {
        // fp32 global loads + in-register convert (no separate convert pass)
        s8v a0 = cvt8(*(const float4*)(ag + k0),
                      *(const float4*)(ag + k0 + 4));
        s8v a1 = cvt8(*(const float4*)(ag + rstep + k0),
                      *(const float4*)(ag + rstep + k0 + 4));
        s8v b0 = cvt8(*(const float4*)(bg + k0),
                      *(const float4*)(bg + k0 + 4));
        s8v b1 = cvt8(*(const float4*)(bg + rstep + k0),
                      *(const float4*)(bg + rstep + k0 + 4));
        __syncthreads();                 // prior iter's ds_reads done
        *(s8v*)&As[t * 8]         = a0;
        *(s8v*)&As[(256 + t) * 8] = a1;
        *(s8v*)&Bs[t * 8]         = b0;
        *(s8v*)&Bs[(256 + t) * 8] = b1;
        __syncthreads();

        h8 a[4], b[4];
        #pragma unroll
        for (int i = 0; i < 4; i++) {
            a[i] = *(const h8*)&As[(wr * 64 + i * 16 + l15) * 32 + quad * 8];
            b[i] = *(const h8*)&Bs[(wc * 64 + i * 16 + l15) * 32 + quad * 8];
        }
        #pragma unroll
        for (int mt = 0; mt < 4; mt++)
            #pragma unroll
            for (int nt = 0; nt < 4; nt++)
                acc[mt][nt] = MFMAH(a[mt], b[nt], acc[mt][nt]);
    }

    if (wsel < 2) {
        // ---- Q/K: fused RoPE, fp16 stores [B,H,S,D]; K: fused max-norm ----
        u16* OF = (wsel == 0) ? QF : KF;
        float kn_max = 0.f;
        #pragma unroll
        for (int mt = 0; mt < 4; mt++) {
            #pragma unroll
            for (int r = 0; r < 4; r++) {
                int m = m0b + wr * 64 + mt * 16 + quad * 4 + r;
                int b = m >> 11;
                int s = m & 2047;
                float rowsum = 0.f;
                #pragma unroll
                for (int nt = 0; nt < 2; nt++) {
                    int n1 = n0 + wc * 64 + nt * 16 + l15;
                    int dd = n1 & 31;
                    float v1 = acc[mt][nt][r]     + bias[n1];
                    float v2 = acc[mt][nt + 2][r] + bias[n1 + 32];
                    float inv = __expf(-(float)dd * 0.2878231366f); // 1e4^(-dd/32)
                    float ang = (float)s * inv;
                    float c  = cosf(ang);
                    float sn = sinf(ang);
                    float r1 = v1 * c - v2 * sn;
                    float r2 = v2 * c + v1 * sn;
                    rowsum += v1 * v1 + v2 * v2;     // norm is RoPE-invariant
                    int h = n1 >> 6;
                    int d = n1 & 63;
                    size_t base = (((size_t)b * NH + h) * SEQ + s) << 6;
                    OF[base + d]      = f32_to_f16(r1);
                    OF[base + d + 32] = f32_to_f16(r2);
                }
                if (wsel == 1) {
                    rowsum += __shfl_xor(rowsum, 1, 64);
                    rowsum += __shfl_xor(rowsum, 2, 64);
                    rowsum += __shfl_xor(rowsum, 4, 64);
                    rowsum += __shfl_xor(rowsum, 8, 64);
                    kn_max = fmaxf(kn_max, rowsum);
                }
            }
        }
        if (wsel == 1) {
            kn_max = fmaxf(kn_max, __shfl_xor(kn_max, 16, 64));
            kn_max = fmaxf(kn_max, __shfl_xor(kn_max, 32, 64));
            if (lane == 0) atomicMax((int*)km2, __float_as_int(kn_max));
        }
    } else {
        // ---- V: transpose via LDS, fp16 [B,H,D,S], 16-B stores ----
        const int b  = m0b >> 11;
        const int s0 = m0b & 2047;
        const int h0 = (blockIdx.y & 7) * 2;
        __syncthreads();
        #pragma unroll
        for (int mt = 0; mt < 4; mt++) {
            #pragma unroll
            for (int nt = 0; nt < 4; nt++) {
                int n = wc * 64 + nt * 16 + l15;
                float bv_ = bias[n0 + n];
                #pragma unroll
                for (int r = 0; r < 4; r++) {
                    int m = wr * 64 + mt * 16 + quad * 4 + r;
                    float v = acc[mt][nt][r] + bv_;
                    SMEM[n * 128 + ((((m >> 3) ^ (n & 15))) << 3) + (m & 7)] = f32_to_f16(v);
                }
            }
        }
        __syncthreads();
        int n = t >> 1;
        int half = t & 1;
        int d  = n & 63;
        int hh = n >> 6;
        size_t obase = ((size_t)((b * NH + h0 + hh) * HD + d)) * SEQ + s0;
        #pragma unroll
        for (int c = 0; c < 8; c++) {
            int mc = half * 8 + c;
            s8v val = *(const s8v*)&SMEM[n * 128 + ((mc ^ (n & 15)) << 3)];
            *(s8v*)(VtF + obase + mc * 8) = val;
        }
    }
}

// ---------------------------------------------------------------------------
// MFMA flash attention, fp16, static-bound softmax, Q-tile 128, and 64 keys
// staged per barrier pair (2 x 32-key subtiles -> 32 MFMA per barrier).
// Q,K fp16 [B,H,S,D]; V fp16 [B,H,D,S]. AO out fp16 [B,S,H,D].
// ---------------------------------------------------------------------------
__global__ __launch_bounds__(256, 4)
void flash_attn(const u16* __restrict__ QF, const u16* __restrict__ KF,
                const u16* __restrict__ VtF,
                const float* __restrict__ kmax2,
                u16* __restrict__ AOF) {
    __shared__ __align__(16) u16 KS[2][32 * 72];
    __shared__ __align__(16) u16 VtS[2][64 * 40];
    __shared__ __align__(16) u16 PS[128 * 40];

    const int t    = threadIdx.x;
    const int w    = t >> 6;
    const int lane = t & 63;
    const int quad = lane >> 4;
    const int l15  = lane & 15;

    const int q0 = blockIdx.x * 128;
    const int bh = blockIdx.y;
    const size_t kvbase = (size_t)bh * SEQ * HD;
    const float km2 = kmax2[0];

    // ---- Q fragments for both row-tiles; static softmax bounds ----
    h8 qf[2][2];
    float m0[2][4];
    #pragma unroll
    for (int g = 0; g < 2; g++) {
        const u16* qp = QF + kvbase +
            (size_t)(q0 + g * 64 + w * 16 + l15) * HD + quad * 8;
        qf[g][0] = *(const h8*)qp;
        qf[g][1] = *(const h8*)(qp + 32);
        float qn2 = 0.f;
        #pragma unroll
        for (int st = 0; st < 2; st++)
            #pragma unroll
            for (int e = 0; e < 8; e++) {
                float v = (float)qf[g][st][e];
                qn2 += v * v;
            }
        qn2 += __shfl_xor(qn2, 16, 64);
        qn2 += __shfl_xor(qn2, 32, 64);
        #pragma unroll
        for (int r = 0; r < 4; r++) {
            int src = (lane & 48) | (quad * 4 + r);
            float qr = __shfl(qn2, src, 64);
            m0[g][r] = sqrtf(qr * km2) * 0.125f;
        }
    }

    f4v o[2][4];
    float lsum[2][4];
    #pragma unroll
    for (int g = 0; g < 2; g++)
        #pragma unroll
        for (int nt = 0; nt < 4; nt++) {
            o[g][nt] = (f4v){0.f, 0.f, 0.f, 0.f};
            lsum[g][nt] = 0.f;
        }

    for (int k0 = 0; k0 < SEQ; k0 += 64) {
        __syncthreads();

        // ---- stage two K subtiles (each 32 keys x 64 d) ----
        {
            int row = t >> 3;
            int dc  = (t & 7) * 8;
            *(s8v*)&KS[0][row * 72 + dc] =
                *(const s8v*)(KF + kvbase + (size_t)(k0 + row) * HD + dc);
            *(s8v*)&KS[1][row * 72 + dc] =
                *(const s8v*)(KF + kvbase + (size_t)(k0 + 32 + row) * HD + dc);
        }
        // ---- stage two V subtiles (64 d x 32 keys, swizzled) ----
        {
            int d  = t >> 2;
            int kc = (t & 3) * 8;
            size_t g = (size_t)bh * HD * SEQ + (size_t)d * SEQ + k0 + kc;
            int col = kc ^ (((d >> 3) & 3) << 3);
            *(s8v*)&VtS[0][d * 40 + col] = *(const s8v*)(VtF + g);
            *(s8v*)&VtS[1][d * 40 + col] = *(const s8v*)(VtF + g + 32);
        }
        __syncthreads();

        #pragma unroll
        for (int sub = 0; sub < 2; sub++) {
            const u16* kb0 = KS[sub] + l15 * 72 + quad * 8;
            const u16* kb1 = KS[sub] + (16 + l15) * 72 + quad * 8;
            h8 kh0 = *(const h8*)kb0, kh1 = *(const h8*)(kb0 + 32);
            h8 kh2 = *(const h8*)kb1, kh3 = *(const h8*)(kb1 + 32);

            #pragma unroll
            for (int g = 0; g < 2; g++) {
                // ---- QK^T: 16 q-rows x 32 keys ----
                f4v s0 = (f4v){0.f, 0.f, 0.f, 0.f};
                f4v s1 = (f4v){0.f, 0.f, 0.f, 0.f};
                s0 = MFMAH(qf[g][0], kh0, s0);
                s0 = MFMAH(qf[g][1], kh1, s0);
                s1 = MFMAH(qf[g][0], kh2, s1);
                s1 = MFMAH(qf[g][1], kh3, s1);

                // ---- static softmax: p = exp(s/8 - m0) ----
                #pragma unroll
                for (int r = 0; r < 4; r++) {
                    float p0 = __expf(s0[r] * 0.125f - m0[g][r]);
                    float p1 = __expf(s1[r] * 0.125f - m0[g][r]);
                    lsum[g][r] += p0 + p1;
                    int row_l = g * 64 + w * 16 + quad * 4 + r;
                    int cs = row_l & 8;
                    PS[row_l * 40 + (l15 ^ cs)]        = f32_to_f16(p0);
                    PS[row_l * 40 + ((16 + l15) ^ cs)] = f32_to_f16(p1);
                }

                // ---- PV (P rows wave-private; no barrier) ----
                const int prow = g * 64 + w * 16 + l15;
                h8 ph = *(const h8*)&PS[prow * 40 + ((quad * 8) ^ (prow & 8))];
                #pragma unroll
                for (int nt = 0; nt < 4; nt++) {
                    int dim = nt * 16 + l15;
                    int voff = dim * 40 + ((quad * 8) ^ (((dim >> 3) & 3) << 3));
                    o[g][nt] = MFMAH(ph, *(const h8*)&VtS[sub][voff], o[g][nt]);
                }
            }
        }
    }

    // ---- epilogue: reduce l, normalize, write fp16 [B,S,H,D] ----
    const int b = bh >> 4;
    const int h = bh & 15;
    #pragma unroll
    for (int g = 0; g < 2; g++) {
        #pragma unroll
        for (int r = 0; r < 4; r++) {
            float l = lsum[g][r];
            l += __shfl_xor(l, 1, 64);
            l += __shfl_xor(l, 2, 64);
            l += __shfl_xor(l, 4, 64);
            l += __shfl_xor(l, 8, 64);
            float inv_l = 1.0f / l;
            int s = q0 + g * 64 + w * 16 + quad * 4 + r;
            size_t obase = (((size_t)b * SEQ + s) * NH + h) * HD;
            #pragma unroll
            for (int nt = 0; nt < 4; nt++) {
                AOF[obase + nt * 16 + l15] = f32_to_f16(o[g][nt][r] * inv_l);
            }
        }
    }
}

// ---------------------------------------------------------------------------
// Out-projection fp16 MFMA GEMM; A fp16 (flash out), B staged from fp32 Wo
// with inline conversion. fp32 output [m*1024 + n].
// ---------------------------------------------------------------------------
__global__ __launch_bounds__(256, 2)
void gemm_out(const u16* __restrict__ AF, const float* __restrict__ Wo,
              const float* __restrict__ bias, float* __restrict__ out) {
    __shared__ __align__(16) u16 As[128 * 32];
    __shared__ __align__(16) u16 Bs[128 * 32];

    const int t    = threadIdx.x;
    const int w    = t >> 6;
    const int lane = t & 63;
    const int quad = lane >> 4;
    const int l15  = lane & 15;
    const int wr   = w >> 1;
    const int wc   = w & 1;
    const int m0   = blockIdx.x * 128;
    const int n0   = blockIdx.y * 128;

    const int srow = t >> 2;
    const int scol = (t & 3) * 8;
    const u16*   ag = AF + (size_t)(m0 + srow) * KDIM + scol;
    const float* bg = Wo + (size_t)(n0 + srow) * KDIM + scol;
    const size_t rstep = (size_t)64 * KDIM;

    f4v acc[4][4];
    #pragma unroll
    for (int i = 0; i < 4; i++)
        #pragma unroll
        for (int j = 0; j < 4; j++)
            acc[i][j] = (f4v){0.f, 0.f, 0.f, 0.f};

    for (int k0 = 0; k0 < KDIM; k0 += 32) {
        s8v a0 = *(const s8v*)(ag + k0);
        s8v a1 = *(const s8v*)(ag + rstep + k0);
        s8v b0 = cvt8(*(const float4*)(bg + k0),
                      *(const float4*)(bg + k0 + 4));
        s8v b1 = cvt8(*(const float4*)(bg + rstep + k0),
                      *(const float4*)(bg + rstep + k0 + 4));
        __syncthreads();
        *(s8v*)&As[t * 8]         = a0;
        *(s8v*)&As[(256 + t) * 8] = a1;
        *(s8v*)&Bs[t * 8]         = b0;
        *(s8v*)&Bs[(256 + t) * 8] = b1;
        __syncthreads();

        h8 a[4], b[4];
        #pragma unroll
        for (int i = 0; i < 4; i++) {
            a[i] = *(const h8*)&As[(wr * 64 + i * 16 + l15) * 32 + quad * 8];
            b[i] = *(const h8*)&Bs[(wc * 64 + i * 16 + l15) * 32 + quad * 8];
        }
        #pragma unroll
        for (int mt = 0; mt < 4; mt++)
            #pragma unroll
            for (int nt = 0; nt < 4; nt++)
                acc[mt][nt] = MFMAH(a[mt], b[nt], acc[mt][nt]);
    }

    #pragma unroll
    for (int mt = 0; mt < 4; mt++) {
        #pragma unroll
        for (int nt = 0; nt < 4; nt++) {
            int n = n0 + wc * 64 + nt * 16 + l15;
            float bv = bias[n];
            #pragma unroll
            for (int r = 0; r < 4; r++) {
                int m = m0 + wr * 64 + mt * 16 + quad * 4 + r;
                out[(size_t)m * 1024 + n] = acc[mt][nt][r] + bv;
            }
        }
    }
}

// ---------------------------------------------------------------------------
extern "C" void kernel_launch(void* const* d_in, const int* in_sizes, int n_in,
                              void* d_out, int out_size, void* d_ws, size_t ws_size,
                              hipStream_t stream) {
    const float* x  = (const float*)d_in[0];
    const float* Wq = (const float*)d_in[1];
    const float* bq = (const float*)d_in[2];
    const float* Wk = (const float*)d_in[3];
    const float* bk = (const float*)d_in[4];
    const float* Wv = (const float*)d_in[5];
    const float* bv = (const float*)d_in[6];
    const float* Wo = (const float*)d_in[7];
    const float* bo = (const float*)d_in[8];
    float* out = (float*)d_out;

    const size_t TEN = (size_t)MROWS * KDIM;     // 4,194,304

    u16* QF  = (u16*)d_ws;
    u16* KF  = QF + TEN;
    u16* VtF = KF + TEN;
    u16* AOF = VtF + TEN;
    float* km2 = (float*)(AOF + TEN);

    hipMemsetAsync(km2, 0, 4, stream);

    qkv_gemm<<<dim3(32, 24), 256, 0, stream>>>(x, Wq, Wk, Wv,
                                               bq, bk, bv, QF, KF, VtF, km2);

    flash_attn<<<dim3(SEQ / 128, BATCH * NH), 256, 0, stream>>>(
        QF, KF, VtF, km2, AOF);

    gemm_out<<<dim3(MROWS / 128, KDIM / 128), 256, 0, stream>>>(
        AOF, Wo, bo, out);
}

// Round 9
// 405.102 us; speedup vs baseline: 1.2522x; 1.2522x over previous
//
#include <hip/hip_runtime.h>
#include <hip/hip_fp16.h>
#include <math.h>

#define D_MODEL 1024
#define NH 16
#define HD 64
#define SEQ 2048
#define BATCH 2
#define MROWS (BATCH*SEQ)   // 4096
#define KDIM 1024

typedef unsigned short u16;
typedef __attribute__((ext_vector_type(8))) _Float16 h8;   // 8 f16 (4 VGPRs)
typedef __attribute__((ext_vector_type(8))) short s8v;
typedef __attribute__((ext_vector_type(4))) float f4v;

#define MFMAH(a, b, c) __builtin_amdgcn_mfma_f32_16x16x32_f16(a, b, c, 0, 0, 0)

__device__ __forceinline__ u16 f32_to_f16(float f) {
    return __half_as_ushort(__float2half(f));   // v_cvt_f16_f32, RNE
}
__device__ __forceinline__ float f16_to_f32(u16 h) {
    return __half2float(__ushort_as_half(h));
}

// ---------------------------------------------------------------------------
// fp32 -> fp16 conversion for x (4M) + 4 W (1M each). 8 elems/thread.
// ---------------------------------------------------------------------------
__global__ __launch_bounds__(256)
void convert_f16(const float* __restrict__ x,
                 const float* __restrict__ Wq, const float* __restrict__ Wk,
                 const float* __restrict__ Wv, const float* __restrict__ Wo,
                 u16* __restrict__ xF,
                 u16* __restrict__ WqF, u16* __restrict__ WkF,
                 u16* __restrict__ WvF, u16* __restrict__ WoF) {
    int i = blockIdx.x * 256 + threadIdx.x;
    const float* src;
    u16* dst;
    int idx;
    if (i < (1 << 19)) {
        src = x; dst = xF; idx = i;
    } else {
        int j = i - (1 << 19);
        int w = j >> 17;
        idx = j & ((1 << 17) - 1);
        switch (w) {
            case 0:  src = Wq; dst = WqF; break;
            case 1:  src = Wk; dst = WkF; break;
            case 2:  src = Wv; dst = WvF; break;
            default: src = Wo; dst = WoF; break;
        }
    }
    float4 a = ((const float4*)src)[idx * 2];
    float4 b = ((const float4*)src)[idx * 2 + 1];
    ushort4 o0, o1;
    o0.x = f32_to_f16(a.x); o0.y = f32_to_f16(a.y);
    o0.z = f32_to_f16(a.z); o0.w = f32_to_f16(a.w);
    o1.x = f32_to_f16(b.x); o1.y = f32_to_f16(b.y);
    o1.z = f32_to_f16(b.z); o1.w = f32_to_f16(b.w);
    ((ushort4*)dst)[idx * 2]     = o0;
    ((ushort4*)dst)[idx * 2 + 1] = o1;
}

// ---------------------------------------------------------------------------
// Fused QKV fp16 MFMA GEMM, explicit staging, XCD-swizzled 1D grid (768).
// Per XCD (bid&7): 4 m-tiles x all 24 (wsel,n) tiles -> per-XCD L2 working
// set ~= 2 MB of A + streamed W (was: full A re-read by 24 y-slices).
// Q,K: fused RoPE -> fp16 [B,H,S,D]; K: atomicMax row-norm^2 (RoPE-invariant).
// V: LDS transpose -> fp16 [B,H,D,S].
// ---------------------------------------------------------------------------
__global__ __launch_bounds__(256, 2)
void qkv_gemm(const u16* __restrict__ xF, const u16* __restrict__ WqF,
              const u16* __restrict__ WkF, const u16* __restrict__ WvF,
              const float* __restrict__ bq, const float* __restrict__ bk,
              const float* __restrict__ bv,
              u16* __restrict__ QF, u16* __restrict__ KF,
              u16* __restrict__ VtF, float* __restrict__ km2) {
    __shared__ __align__(16) u16 SMEM[16384];   // 32 KB; K-loop uses first 16 KB
    u16* As = SMEM;                 // [128][32] f16
    u16* Bs = SMEM + 4096;

    const int t    = threadIdx.x;
    const int w    = t >> 6;
    const int lane = t & 63;
    const int quad = lane >> 4;
    const int l15  = lane & 15;
    const int wr   = w >> 1;
    const int wc   = w & 1;

    // XCD-aware decode: xcd = bid&7 owns m-tiles [xcd*4, xcd*4+4)
    const int bid  = blockIdx.x;
    const int xcd  = bid & 7;
    const int j    = bid >> 3;          // 0..95
    const int m0b  = (xcd * 4 + (j & 3)) * 128;
    const int yt   = j >> 2;            // 0..23
    const int wsel = yt >> 3;
    const int n0   = (yt & 7) * 128;

    const u16* Bg;
    const float* bias;
    if (wsel == 0)      { Bg = WqF; bias = bq; }
    else if (wsel == 1) { Bg = WkF; bias = bk; }
    else                { Bg = WvF; bias = bv; }

    const int srow = t >> 2;            // 0..63
    const int scol = (t & 3) * 8;
    const u16* ag = xF + (size_t)(m0b + srow) * KDIM + scol;
    const u16* bg = Bg + (size_t)(n0 + srow) * KDIM + scol;
    const size_t rstep = (size_t)64 * KDIM;

    f4v acc[4][4];
    #pragma unroll
    for (int i = 0; i < 4; i++)
        #pragma unroll
        for (int jj = 0; jj < 4; jj++)
            acc[i][jj] = (f4v){0.f, 0.f, 0.f, 0.f};

    for (int k0 = 0; k0 < KDIM; k0 += 32) {
        s8v a0 = *(const s8v*)(ag + k0);
        s8v a1 = *(const s8v*)(ag + rstep + k0);
        s8v b0 = *(const s8v*)(bg + k0);
        s8v b1 = *(const s8v*)(bg + rstep + k0);
        __syncthreads();                 // prior iter's ds_reads done
        *(s8v*)&As[t * 8]         = a0;
        *(s8v*)&As[(256 + t) * 8] = a1;
        *(s8v*)&Bs[t * 8]         = b0;
        *(s8v*)&Bs[(256 + t) * 8] = b1;
        __syncthreads();

        h8 a[4], b[4];
        #pragma unroll
        for (int i = 0; i < 4; i++) {
            a[i] = *(const h8*)&As[(wr * 64 + i * 16 + l15) * 32 + quad * 8];
            b[i] = *(const h8*)&Bs[(wc * 64 + i * 16 + l15) * 32 + quad * 8];
        }
        #pragma unroll
        for (int mt = 0; mt < 4; mt++)
            #pragma unroll
            for (int nt = 0; nt < 4; nt++)
                acc[mt][nt] = MFMAH(a[mt], b[nt], acc[mt][nt]);
    }

    if (wsel < 2) {
        // ---- Q/K: fused RoPE, fp16 stores [B,H,S,D]; K: fused max-norm ----
        u16* OF = (wsel == 0) ? QF : KF;
        float kn_max = 0.f;
        #pragma unroll
        for (int mt = 0; mt < 4; mt++) {
            #pragma unroll
            for (int r = 0; r < 4; r++) {
                int m = m0b + wr * 64 + mt * 16 + quad * 4 + r;
                int b = m >> 11;
                int s = m & 2047;
                float rowsum = 0.f;
                #pragma unroll
                for (int nt = 0; nt < 2; nt++) {
                    int n1 = n0 + wc * 64 + nt * 16 + l15;
                    int dd = n1 & 31;
                    float v1 = acc[mt][nt][r]     + bias[n1];
                    float v2 = acc[mt][nt + 2][r] + bias[n1 + 32];
                    float inv = __expf(-(float)dd * 0.2878231366f); // 1e4^(-dd/32)
                    float ang = (float)s * inv;
                    float c  = cosf(ang);
                    float sn = sinf(ang);
                    float r1 = v1 * c - v2 * sn;
                    float r2 = v2 * c + v1 * sn;
                    rowsum += v1 * v1 + v2 * v2;     // norm is RoPE-invariant
                    int h = n1 >> 6;
                    int d = n1 & 63;
                    size_t base = (((size_t)b * NH + h) * SEQ + s) << 6;
                    OF[base + d]      = f32_to_f16(r1);
                    OF[base + d + 32] = f32_to_f16(r2);
                }
                if (wsel == 1) {
                    rowsum += __shfl_xor(rowsum, 1, 64);
                    rowsum += __shfl_xor(rowsum, 2, 64);
                    rowsum += __shfl_xor(rowsum, 4, 64);
                    rowsum += __shfl_xor(rowsum, 8, 64);
                    kn_max = fmaxf(kn_max, rowsum);
                }
            }
        }
        if (wsel == 1) {
            kn_max = fmaxf(kn_max, __shfl_xor(kn_max, 16, 64));
            kn_max = fmaxf(kn_max, __shfl_xor(kn_max, 32, 64));
            if (lane == 0) atomicMax((int*)km2, __float_as_int(kn_max));
        }
    } else {
        // ---- V: transpose via LDS, fp16 [B,H,D,S], 16-B stores ----
        const int b  = m0b >> 11;
        const int s0 = m0b & 2047;
        const int h0 = (yt & 7) * 2;
        __syncthreads();
        #pragma unroll
        for (int mt = 0; mt < 4; mt++) {
            #pragma unroll
            for (int nt = 0; nt < 4; nt++) {
                int n = wc * 64 + nt * 16 + l15;
                float bv_ = bias[n0 + n];
                #pragma unroll
                for (int r = 0; r < 4; r++) {
                    int m = wr * 64 + mt * 16 + quad * 4 + r;
                    float v = acc[mt][nt][r] + bv_;
                    SMEM[n * 128 + ((((m >> 3) ^ (n & 15))) << 3) + (m & 7)] = f32_to_f16(v);
                }
            }
        }
        __syncthreads();
        int n = t >> 1;
        int half = t & 1;
        int d  = n & 63;
        int hh = n >> 6;
        size_t obase = ((size_t)((b * NH + h0 + hh) * HD + d)) * SEQ + s0;
        #pragma unroll
        for (int c = 0; c < 8; c++) {
            int mc = half * 8 + c;
            s8v val = *(const s8v*)&SMEM[n * 128 + ((mc ^ (n & 15)) << 3)];
            *(s8v*)(VtF + obase + mc * 8) = val;
        }
    }
}

// ---------------------------------------------------------------------------
// MFMA flash attention, fp16, static-bound softmax, Q-tile 128, 64 keys per
// barrier (2 x 32-key subtiles). XCD-swizzled 1D grid (512): 4 heads per XCD
// -> per-XCD KV working set 2 MB (L2-resident).
// ---------------------------------------------------------------------------
__global__ __launch_bounds__(256, 4)
void flash_attn(const u16* __restrict__ QF, const u16* __restrict__ KF,
                const u16* __restrict__ VtF,
                const float* __restrict__ kmax2,
                u16* __restrict__ AOF) {
    __shared__ __align__(16) u16 KS[2][32 * 72];
    __shared__ __align__(16) u16 VtS[2][64 * 40];
    __shared__ __align__(16) u16 PS[128 * 40];

    const int t    = threadIdx.x;
    const int w    = t >> 6;
    const int lane = t & 63;
    const int quad = lane >> 4;
    const int l15  = lane & 15;

    // XCD-aware decode: xcd owns heads [xcd*4, xcd*4+4)
    const int bid = blockIdx.x;
    const int xcd = bid & 7;
    const int j   = bid >> 3;          // 0..63
    const int bh  = xcd * 4 + (j & 3); // 0..31
    const int q0  = (j >> 2) * 128;    // 0..15 * 128

    const size_t kvbase = (size_t)bh * SEQ * HD;
    const float km2 = kmax2[0];

    // ---- Q fragments for both row-tiles; static softmax bounds ----
    h8 qf[2][2];
    float m0[2][4];
    #pragma unroll
    for (int g = 0; g < 2; g++) {
        const u16* qp = QF + kvbase +
            (size_t)(q0 + g * 64 + w * 16 + l15) * HD + quad * 8;
        qf[g][0] = *(const h8*)qp;
        qf[g][1] = *(const h8*)(qp + 32);
        float qn2 = 0.f;
        #pragma unroll
        for (int st = 0; st < 2; st++)
            #pragma unroll
            for (int e = 0; e < 8; e++) {
                float v = (float)qf[g][st][e];
                qn2 += v * v;
            }
        qn2 += __shfl_xor(qn2, 16, 64);
        qn2 += __shfl_xor(qn2, 32, 64);
        #pragma unroll
        for (int r = 0; r < 4; r++) {
            int src = (lane & 48) | (quad * 4 + r);
            float qr = __shfl(qn2, src, 64);
            m0[g][r] = sqrtf(qr * km2) * 0.125f;
        }
    }

    f4v o[2][4];
    float lsum[2][4];
    #pragma unroll
    for (int g = 0; g < 2; g++)
        #pragma unroll
        for (int nt = 0; nt < 4; nt++) {
            o[g][nt] = (f4v){0.f, 0.f, 0.f, 0.f};
            lsum[g][nt] = 0.f;
        }

    for (int k0 = 0; k0 < SEQ; k0 += 64) {
        __syncthreads();

        // ---- stage two K subtiles (each 32 keys x 64 d) ----
        {
            int row = t >> 3;
            int dc  = (t & 7) * 8;
            *(s8v*)&KS[0][row * 72 + dc] =
                *(const s8v*)(KF + kvbase + (size_t)(k0 + row) * HD + dc);
            *(s8v*)&KS[1][row * 72 + dc] =
                *(const s8v*)(KF + kvbase + (size_t)(k0 + 32 + row) * HD + dc);
        }
        // ---- stage two V subtiles (64 d x 32 keys, swizzled) ----
        {
            int d  = t >> 2;
            int kc = (t & 3) * 8;
            size_t g = (size_t)bh * HD * SEQ + (size_t)d * SEQ + k0 + kc;
            int col = kc ^ (((d >> 3) & 3) << 3);
            *(s8v*)&VtS[0][d * 40 + col] = *(const s8v*)(VtF + g);
            *(s8v*)&VtS[1][d * 40 + col] = *(const s8v*)(VtF + g + 32);
        }
        __syncthreads();

        #pragma unroll
        for (int sub = 0; sub < 2; sub++) {
            const u16* kb0 = KS[sub] + l15 * 72 + quad * 8;
            const u16* kb1 = KS[sub] + (16 + l15) * 72 + quad * 8;
            h8 kh0 = *(const h8*)kb0, kh1 = *(const h8*)(kb0 + 32);
            h8 kh2 = *(const h8*)kb1, kh3 = *(const h8*)(kb1 + 32);

            #pragma unroll
            for (int g = 0; g < 2; g++) {
                f4v s0 = (f4v){0.f, 0.f, 0.f, 0.f};
                f4v s1 = (f4v){0.f, 0.f, 0.f, 0.f};
                s0 = MFMAH(qf[g][0], kh0, s0);
                s0 = MFMAH(qf[g][1], kh1, s0);
                s1 = MFMAH(qf[g][0], kh2, s1);
                s1 = MFMAH(qf[g][1], kh3, s1);

                #pragma unroll
                for (int r = 0; r < 4; r++) {
                    float p0 = __expf(s0[r] * 0.125f - m0[g][r]);
                    float p1 = __expf(s1[r] * 0.125f - m0[g][r]);
                    lsum[g][r] += p0 + p1;
                    int row_l = g * 64 + w * 16 + quad * 4 + r;
                    int cs = row_l & 8;
                    PS[row_l * 40 + (l15 ^ cs)]        = f32_to_f16(p0);
                    PS[row_l * 40 + ((16 + l15) ^ cs)] = f32_to_f16(p1);
                }

                const int prow = g * 64 + w * 16 + l15;
                h8 ph = *(const h8*)&PS[prow * 40 + ((quad * 8) ^ (prow & 8))];
                #pragma unroll
                for (int nt = 0; nt < 4; nt++) {
                    int dim = nt * 16 + l15;
                    int voff = dim * 40 + ((quad * 8) ^ (((dim >> 3) & 3) << 3));
                    o[g][nt] = MFMAH(ph, *(const h8*)&VtS[sub][voff], o[g][nt]);
                }
            }
        }
    }

    // ---- epilogue: reduce l, normalize, write fp16 [B,S,H,D] ----
    const int b = bh >> 4;
    const int h = bh & 15;
    #pragma unroll
    for (int g = 0; g < 2; g++) {
        #pragma unroll
        for (int r = 0; r < 4; r++) {
            float l = lsum[g][r];
            l += __shfl_xor(l, 1, 64);
            l += __shfl_xor(l, 2, 64);
            l += __shfl_xor(l, 4, 64);
            l += __shfl_xor(l, 8, 64);
            float inv_l = 1.0f / l;
            int s = q0 + g * 64 + w * 16 + quad * 4 + r;
            size_t obase = (((size_t)b * SEQ + s) * NH + h) * HD;
            #pragma unroll
            for (int nt = 0; nt < 4; nt++) {
                AOF[obase + nt * 16 + l15] = f32_to_f16(o[g][nt][r] * inv_l);
            }
        }
    }
}

// ---------------------------------------------------------------------------
// Out-projection fp16 MFMA GEMM, explicit staging, XCD-swizzled 1D grid (256):
// per XCD 4 m-tiles x 8 n-tiles -> working set ~3 MB (A 1 MB + Wo 2 MB).
// ---------------------------------------------------------------------------
__global__ __launch_bounds__(256, 2)
void gemm_out(const u16* __restrict__ AF, const u16* __restrict__ BF,
              const float* __restrict__ bias, float* __restrict__ out) {
    __shared__ __align__(16) u16 As[128 * 32];
    __shared__ __align__(16) u16 Bs[128 * 32];

    const int t    = threadIdx.x;
    const int w    = t >> 6;
    const int lane = t & 63;
    const int quad = lane >> 4;
    const int l15  = lane & 15;
    const int wr   = w >> 1;
    const int wc   = w & 1;

    const int bid = blockIdx.x;
    const int xcd = bid & 7;
    const int j   = bid >> 3;              // 0..31
    const int m0  = (xcd * 4 + (j & 3)) * 128;
    const int n0  = (j >> 2) * 128;        // 0..7 * 128

    const int srow = t >> 2;
    const int scol = (t & 3) * 8;
    const u16* ag = AF + (size_t)(m0 + srow) * KDIM + scol;
    const u16* bg = BF + (size_t)(n0 + srow) * KDIM + scol;
    const size_t rstep = (size_t)64 * KDIM;

    f4v acc[4][4];
    #pragma unroll
    for (int i = 0; i < 4; i++)
        #pragma unroll
        for (int jj = 0; jj < 4; jj++)
            acc[i][jj] = (f4v){0.f, 0.f, 0.f, 0.f};

    for (int k0 = 0; k0 < KDIM; k0 += 32) {
        s8v a0 = *(const s8v*)(ag + k0);
        s8v a1 = *(const s8v*)(ag + rstep + k0);
        s8v b0 = *(const s8v*)(bg + k0);
        s8v b1 = *(const s8v*)(bg + rstep + k0);
        __syncthreads();
        *(s8v*)&As[t * 8]         = a0;
        *(s8v*)&As[(256 + t) * 8] = a1;
        *(s8v*)&Bs[t * 8]         = b0;
        *(s8v*)&Bs[(256 + t) * 8] = b1;
        __syncthreads();

        h8 a[4], b[4];
        #pragma unroll
        for (int i = 0; i < 4; i++) {
            a[i] = *(const h8*)&As[(wr * 64 + i * 16 + l15) * 32 + quad * 8];
            b[i] = *(const h8*)&Bs[(wc * 64 + i * 16 + l15) * 32 + quad * 8];
        }
        #pragma unroll
        for (int mt = 0; mt < 4; mt++)
            #pragma unroll
            for (int nt = 0; nt < 4; nt++)
                acc[mt][nt] = MFMAH(a[mt], b[nt], acc[mt][nt]);
    }

    #pragma unroll
    for (int mt = 0; mt < 4; mt++) {
        #pragma unroll
        for (int nt = 0; nt < 4; nt++) {
            int n = n0 + wc * 64 + nt * 16 + l15;
            float bv = bias[n];
            #pragma unroll
            for (int r = 0; r < 4; r++) {
                int m = m0 + wr * 64 + mt * 16 + quad * 4 + r;
                out[(size_t)m * 1024 + n] = acc[mt][nt][r] + bv;
            }
        }
    }
}

// ---------------------------------------------------------------------------
extern "C" void kernel_launch(void* const* d_in, const int* in_sizes, int n_in,
                              void* d_out, int out_size, void* d_ws, size_t ws_size,
                              hipStream_t stream) {
    const float* x  = (const float*)d_in[0];
    const float* Wq = (const float*)d_in[1];
    const float* bq = (const float*)d_in[2];
    const float* Wk = (const float*)d_in[3];
    const float* bk = (const float*)d_in[4];
    const float* Wv = (const float*)d_in[5];
    const float* bv = (const float*)d_in[6];
    const float* Wo = (const float*)d_in[7];
    const float* bo = (const float*)d_in[8];
    float* out = (float*)d_out;

    const size_t TEN = (size_t)MROWS * KDIM;     // 4,194,304
    const size_t WSZ = (size_t)KDIM * KDIM;      // 1,048,576

    u16* xF  = (u16*)d_ws;
    u16* WqF = xF + TEN;
    u16* WkF = WqF + WSZ;
    u16* WvF = WkF + WSZ;
    u16* WoF = WvF + WSZ;
    u16* QF  = WoF + WSZ;
    u16* KF  = QF + TEN;
    u16* VtF = KF + TEN;
    float* km2 = (float*)(VtF + TEN);
    u16* AOF = xF;          // x dead after qkv_gemm

    convert_f16<<<4096, 256, 0, stream>>>(x, Wq, Wk, Wv, Wo,
                                          xF, WqF, WkF, WvF, WoF);

    hipMemsetAsync(km2, 0, 4, stream);

    qkv_gemm<<<768, 256, 0, stream>>>(xF, WqF, WkF, WvF,
                                      bq, bk, bv, QF, KF, VtF, km2);

    flash_attn<<<512, 256, 0, stream>>>(QF, KF, VtF, km2, AOF);

    gemm_out<<<256, 256, 0, stream>>>(AOF, WoF, bo, out);
}